// Round 5
// baseline (136.880 us; speedup 1.0000x reference)
//
#include <hip/hip_runtime.h>
#include <math.h>

// ---- Problem constants -----------------------------------------------------
#define NQ        12
#define NPS       14
#define NPATCH    196
#define NB        4
#define NCLS      1000
#define FEATDIM   2352           // 196*12
#define SCALE_F   0.28867513459481287f  // 1/sqrt(12)
#define LSTRIDE   65             // floats per thread region; odd -> conflict-free

// ---- Layouts ----------------------------------------------------------------
// 64-thread block, 64 amps/thread: 6 state bits in registers, 6 in tid.
// qubit q <-> state bit position (11-q). PR[L][j] = state position of reg bit j;
// PT[L][j] = state position of tid bit j. Orderings chosen so all 9 relayout
// transitions have bank-distinct low-5 reader weights (verified mod 32).
constexpr int PR[5][6] = {
    { 6, 7, 8, 9,10,11},   // L1: r5..r0 = q0,q1,q2,q3,q4,q5
    { 2, 3, 4, 5, 6, 7},   // L2: r5..r0 = q4,q5,q6,q7,q8,q9
    { 0, 1, 2, 3, 7,11},   // L3: r5..r0 = q0,q4,q8,q9,q10,q11
    { 1, 2, 5, 6, 9,10},   // L4: r5..r0 = q1,q2,q5,q6,q9,q10
    { 0, 4, 8, 9,10,11},   // L5: r5..r0 = q0,q1,q2,q3,q7,q11
};
constexpr int PT[5][6] = {
    { 0, 1, 2, 3, 4, 5},   // L1: t5..t0 = q6,q7,q8,q9,q10,q11
    { 8, 9, 0, 1,10,11},   // L2: t5..t0 = q0,q1,q10,q11,q2,q3
    { 9, 4, 8, 6, 5,10},   // L3: t5..t0 = q1,q6,q5,q3,q7,q2
    { 0, 8, 4, 7, 3,11},   // L4: t5..t0 = q0,q8,q4,q7,q3,q11
    { 6, 5, 1, 2, 3, 7},   // L5: t5..t0 = q4,q8,q9,q10,q6,q5
};

// weight of state position `pos` in layout-X storage (addr = 65*t + r)
constexpr int wgt(int X, int pos) {
    for (int k = 0; k < 6; ++k) if (PR[X][k] == pos) return 1 << k;
    for (int k = 0; k < 6; ++k) if (PT[X][k] == pos) return LSTRIDE << k;
    return 0;
}
constexpr int rimm(int X, int Y, int r) {
    int s = 0;
    for (int j = 0; j < 6; ++j) if ((r >> j) & 1) s += wgt(X, PR[Y][j]);
    return s;
}

// X,Y are 0-based layout indices. Single buffer; 1-wave block so barriers cheap.
template<int X, int Y>
__device__ __forceinline__ void relayout(float amp[64], float* lds, int tid) {
    float* w = lds + LSTRIDE * tid;
    #pragma unroll
    for (int r = 0; r < 64; ++r) w[r] = amp[r];
    __syncthreads();
    int base = 0;
    #pragma unroll
    for (int j = 0; j < 6; ++j)
        base += ((tid >> j) & 1) ? wgt(X, PT[Y][j]) : 0;
    #pragma unroll
    for (int r = 0; r < 64; ++r)
        amp[r] = lds[base + rimm(X, Y, r)];
    __syncthreads();   // WAR guard before next relayout's writes
}

// RBS gate on register bits MI (first qubit w1) / MJ (second qubit w2).
// Half-angle form: gc = 0.5*cos(2t), gs = 0.5*sin(2t).
template<int MI, int MJ>
__device__ __forceinline__ void apply_gate(float amp[64], float gc, float gs) {
    #pragma unroll
    for (int m = 0; m < 64; ++m) {
        if (m & (MI | MJ)) continue;
        float a0 = amp[m], a1 = amp[m | MJ], a2 = amp[m | MI], a3 = amp[m | MI | MJ];
        float p  = a0 + a1, q  = a0 - a1;
        float p2 = a2 + a3, q2 = a2 - a3;
        float t1 = 0.5f * p  + gc * q  - gs * q2;
        float t2 = 0.5f * p2 + gc * q2 + gs * q;
        amp[m]           = t1;
        amp[m | MJ]      = p  - t1;
        amp[m | MI]      = t2;
        amp[m | MI | MJ] = p2 - t2;
    }
}

// ---- Kernel: fused projection + quantum circuit ----------------------------
// grid (196, 4, 3), block 64 (one wave).
__global__ __launch_bounds__(64) void qcirc_kernel(
    const float* __restrict__ x,      // (4,3,224,224)
    const float* __restrict__ Wp,     // (12,256)
    const float* __restrict__ bproj,  // (12,)
    const float* __restrict__ qp,
    const float* __restrict__ kp,
    const float* __restrict__ vp,
    float* __restrict__ qkv)          // (3,784,12)
{
    __shared__ __align__(16) float lds[64 * LSTRIDE];
    __shared__ float chs[NQ], shs[NQ];
    __shared__ float gC[40], gS[40];
    __shared__ float psum[NQ];

    const int tid = threadIdx.x;
    const int p = blockIdx.x, b = blockIdx.y, c = blockIdx.z;
    const int bp = b * NPATCH + p;
    const float* params = (c == 0) ? qp : (c == 1) ? kp : vp;

    // ---- projection: 4 pixels/thread, butterfly reduce ----
    float part[NQ];
    #pragma unroll
    for (int q = 0; q < NQ; ++q) part[q] = 0.0f;
    {
        int py = p / NPS, px = p % NPS;
        const float* xb = x + (size_t)b * 3 * 224 * 224;
        #pragma unroll
        for (int k = 0; k < 4; ++k) {
            int pix = tid + 64 * k;
            int off = (py * 16 + (pix >> 4)) * 224 + px * 16 + (pix & 15);
            float v = (xb[off] + xb[off + 50176] + xb[off + 100352]) * (1.0f / 3.0f);
            #pragma unroll
            for (int q = 0; q < NQ; ++q) part[q] += v * Wp[q * 256 + pix];
        }
    }
    if (tid < 40) {
        int l = tid / 20, g = tid - l * 20;
        float th = params[l * 32 + g];
        gC[tid] = 0.5f * cosf(2.0f * th);
        gS[tid] = 0.5f * sinf(2.0f * th);
    }
    #pragma unroll
    for (int o = 1; o < 64; o <<= 1) {
        #pragma unroll
        for (int q = 0; q < NQ; ++q) part[q] += __shfl_xor(part[q], o);
    }
    if (tid == 0) {
        #pragma unroll
        for (int q = 0; q < NQ; ++q) psum[q] = part[q];
    }
    __syncthreads();
    if (tid < NQ) {
        float h = 0.5f * (psum[tid] + bproj[tid]);
        chs[tid] = cosf(h); shs[tid] = sinf(h);
    }
    __syncthreads();

    // ---- init in L1 (reg bit j <-> qubit 5-j; tid bit j <-> qubit 11-j) ----
    float amp[64];
    {
        float hi = 1.0f;
        #pragma unroll
        for (int j = 0; j < 6; ++j)
            hi *= ((tid >> j) & 1) ? shs[11 - j] : chs[11 - j];
        float pl[8], ph[8];
        #pragma unroll
        for (int i = 0; i < 8; ++i) {
            pl[i] = ((i & 4) ? shs[0] : chs[0]) * ((i & 2) ? shs[1] : chs[1]) *
                    ((i & 1) ? shs[2] : chs[2]) * hi;
            ph[i] = ((i & 4) ? shs[3] : chs[3]) * ((i & 2) ? shs[4] : chs[4]) *
                    ((i & 1) ? shs[5] : chs[5]);
        }
        #pragma unroll
        for (int r = 0; r < 64; ++r) amp[r] = pl[r >> 3] * ph[r & 7];
    }

    // ---- 2 layers x 5 runs; 9 relayouts total; dep-DAG-verified schedule ----
    #pragma unroll 1
    for (int l = 0; l < 2; ++l) {
        const int bb = l * 20;
        // RunA1 (L1, r5..r0 = q0..q5): p0(0,1) p1(2,3) p2(4,5) p6(0,2) p7(1,3)
        apply_gate<32,16>(amp, gC[bb+0], gS[bb+0]);
        apply_gate< 8, 4>(amp, gC[bb+1], gS[bb+1]);
        apply_gate< 2, 1>(amp, gC[bb+2], gS[bb+2]);
        apply_gate<32, 8>(amp, gC[bb+6], gS[bb+6]);
        apply_gate<16, 4>(amp, gC[bb+7], gS[bb+7]);
        relayout<0,1>(amp, lds, tid);
        // RunA2 (L2, r5..r0 = q4..q9): p3(6,7) p4(8,9) p8(4,6) p9(5,7)
        apply_gate< 8, 4>(amp, gC[bb+3], gS[bb+3]);
        apply_gate< 2, 1>(amp, gC[bb+4], gS[bb+4]);
        apply_gate<32, 8>(amp, gC[bb+8], gS[bb+8]);
        apply_gate<16, 4>(amp, gC[bb+9], gS[bb+9]);
        relayout<1,2>(amp, lds, tid);
        // RunA3 (L3, r5..r0 = q0,q4,q8,q9,q10,q11): p5(10,11) p10(8,10) p11(9,11) p12(0,4) p16(0,8)
        apply_gate< 2, 1>(amp, gC[bb+5],  gS[bb+5]);
        apply_gate< 8, 2>(amp, gC[bb+10], gS[bb+10]);
        apply_gate< 4, 1>(amp, gC[bb+11], gS[bb+11]);
        apply_gate<32,16>(amp, gC[bb+12], gS[bb+12]);
        apply_gate<32, 8>(amp, gC[bb+16], gS[bb+16]);
        relayout<2,3>(amp, lds, tid);
        // RunA4 (L4, r5..r0 = q1,q2,q5,q6,q9,q10): p13(1,5) p14(2,6) p17(1,9) p18(2,10)
        apply_gate<32, 8>(amp, gC[bb+13], gS[bb+13]);
        apply_gate<16, 4>(amp, gC[bb+14], gS[bb+14]);
        apply_gate<32, 2>(amp, gC[bb+17], gS[bb+17]);
        apply_gate<16, 1>(amp, gC[bb+18], gS[bb+18]);
        relayout<3,4>(amp, lds, tid);
        // RunA5 (L5, r5..r0 = q0,q1,q2,q3,q7,q11): p15(3,7) p19(3,11)
        apply_gate< 4, 2>(amp, gC[bb+15], gS[bb+15]);
        apply_gate< 4, 1>(amp, gC[bb+19], gS[bb+19]);
        if (l == 0) relayout<4,0>(amp, lds, tid);
    }

    // ---- expvals in L5: reg q0(b5) q1(b4) q2(b3) q3(b2) q7(b1) q11(b0);
    //      tid: q4(t5) q8(t4) q9(t3) q10(t2) q6(t1) q5(t0) ----
    float Sq11, Sq7, Sq3, Sq2, Sq1, Sq0, T;
    {
        float s1[32]; Sq11 = 0.0f;
        #pragma unroll
        for (int i = 0; i < 32; ++i) {
            float e = amp[2*i] * amp[2*i], o = amp[2*i+1] * amp[2*i+1];
            s1[i] = e + o; Sq11 += e - o;
        }
        float s2[16]; Sq7 = 0.0f;
        #pragma unroll
        for (int i = 0; i < 16; ++i) { s2[i] = s1[2*i] + s1[2*i+1]; Sq7 += s1[2*i] - s1[2*i+1]; }
        float s3[8]; Sq3 = 0.0f;
        #pragma unroll
        for (int i = 0; i < 8; ++i) { s3[i] = s2[2*i] + s2[2*i+1]; Sq3 += s2[2*i] - s2[2*i+1]; }
        float s4[4]; Sq2 = 0.0f;
        #pragma unroll
        for (int i = 0; i < 4; ++i) { s4[i] = s3[2*i] + s3[2*i+1]; Sq2 += s3[2*i] - s3[2*i+1]; }
        float s5[2]; Sq1 = 0.0f;
        #pragma unroll
        for (int i = 0; i < 2; ++i) { s5[i] = s4[2*i] + s4[2*i+1]; Sq1 += s4[2*i] - s4[2*i+1]; }
        T = s5[0] + s5[1]; Sq0 = s5[0] - s5[1];
    }
    // signed butterfly over 6 tid bits
    float A = T, M[6];
    #pragma unroll
    for (int pbit = 0; pbit < 6; ++pbit) {
        int msk = 1 << pbit;
        float Ap = __shfl_xor(A, msk);
        float d  = A - Ap;
        M[pbit] = (tid & msk) ? -d : d;
        A += Ap;
        #pragma unroll
        for (int k = 0; k < 6; ++k)
            if (k < pbit) M[k] += __shfl_xor(M[k], msk);
        Sq0  += __shfl_xor(Sq0,  msk);
        Sq1  += __shfl_xor(Sq1,  msk);
        Sq2  += __shfl_xor(Sq2,  msk);
        Sq3  += __shfl_xor(Sq3,  msk);
        Sq7  += __shfl_xor(Sq7,  msk);
        Sq11 += __shfl_xor(Sq11, msk);
    }
    if (tid == 0) {
        float* out = qkv + ((size_t)c * (NB * NPATCH) + bp) * NQ;
        out[0]  = Sq0;  out[1]  = Sq1;  out[2]  = Sq2;  out[3]  = Sq3;
        out[4]  = M[5]; out[5]  = M[0]; out[6]  = M[1]; out[7]  = Sq7;
        out[8]  = M[4]; out[9]  = M[3]; out[10] = M[2]; out[11] = Sq11;
    }
}

// ---- Kernel: attention ------------------------------------------------------
__global__ __launch_bounds__(256) void attn_kernel(
    const float* __restrict__ qkv,    // (3,784,12)
    float* __restrict__ outb)         // (4,2352)
{
    int tid = threadIdx.x;
    int qp = blockIdx.x, b = blockIdx.y;
    const float* Q = qkv;
    const float* K = qkv + NB * NPATCH * NQ;
    const float* V = qkv + 2 * NB * NPATCH * NQ;

    __shared__ float redm[4], reds[4], redv[4][NQ];

    float qv[NQ];
    #pragma unroll
    for (int d = 0; d < NQ; d++) qv[d] = Q[(b * NPATCH + qp) * NQ + d];

    float score = -1e30f;
    if (tid < NPATCH) {
        float s = 0.0f;
        #pragma unroll
        for (int d = 0; d < NQ; d++) s += qv[d] * K[(b * NPATCH + tid) * NQ + d];
        score = s * SCALE_F;
    }
    float m = score;
    #pragma unroll
    for (int o = 32; o > 0; o >>= 1) m = fmaxf(m, __shfl_down(m, o));
    int lane = tid & 63, wv = tid >> 6;
    if (lane == 0) redm[wv] = m;
    __syncthreads();
    float maxv = fmaxf(fmaxf(redm[0], redm[1]), fmaxf(redm[2], redm[3]));

    float w = (tid < NPATCH) ? expf(score - maxv) : 0.0f;
    float sm = w;
    #pragma unroll
    for (int o = 32; o > 0; o >>= 1) sm += __shfl_down(sm, o);
    if (lane == 0) reds[wv] = sm;

    float part[NQ];
    #pragma unroll
    for (int d = 0; d < NQ; d++) part[d] = 0.0f;
    if (tid < NPATCH) {
        #pragma unroll
        for (int d = 0; d < NQ; d++) part[d] = w * V[(b * NPATCH + tid) * NQ + d];
    }
    #pragma unroll
    for (int d = 0; d < NQ; d++) {
        #pragma unroll
        for (int o = 32; o > 0; o >>= 1) part[d] += __shfl_down(part[d], o);
    }
    if (lane == 0) {
        #pragma unroll
        for (int d = 0; d < NQ; d++) redv[wv][d] = part[d];
    }
    __syncthreads();
    if (tid < NQ) {
        float sumv = reds[0] + reds[1] + reds[2] + reds[3];
        float s = redv[0][tid] + redv[1][tid] + redv[2][tid] + redv[3][tid];
        outb[(size_t)b * FEATDIM + qp * NQ + tid] = s / sumv;
    }
}

// ---- Kernel: classifier -----------------------------------------------------
__global__ __launch_bounds__(256) void cls_kernel(
    const float* __restrict__ outb,   // (4,2352)
    const float* __restrict__ Wc,     // (1000,2352)
    const float* __restrict__ bc,     // (1000,)
    float* __restrict__ logits)       // (4,1000)
{
    int o = blockIdx.x, tid = threadIdx.x;
    float acc[NB] = {0.0f, 0.0f, 0.0f, 0.0f};
    const float* wrow = Wc + (size_t)o * FEATDIM;
    for (int j = tid; j < FEATDIM; j += 256) {
        float w = wrow[j];
        #pragma unroll
        for (int b = 0; b < NB; b++) acc[b] += w * outb[(size_t)b * FEATDIM + j];
    }
    #pragma unroll
    for (int b = 0; b < NB; b++) {
        #pragma unroll
        for (int off = 32; off > 0; off >>= 1) acc[b] += __shfl_down(acc[b], off);
    }
    __shared__ float red[4][NB];
    int lane = tid & 63, wv = tid >> 6;
    if (lane == 0) {
        #pragma unroll
        for (int b = 0; b < NB; b++) red[wv][b] = acc[b];
    }
    __syncthreads();
    if (tid < NB) {
        float s = red[0][tid] + red[1][tid] + red[2][tid] + red[3][tid];
        logits[(size_t)tid * NCLS + o] = s + bc[o];
    }
}

// ---- Launch ----------------------------------------------------------------
extern "C" void kernel_launch(void* const* d_in, const int* in_sizes, int n_in,
                              void* d_out, int out_size, void* d_ws, size_t ws_size,
                              hipStream_t stream) {
    const float* x     = (const float*)d_in[0];
    const float* Wp    = (const float*)d_in[1];
    const float* bproj = (const float*)d_in[2];
    const float* qp    = (const float*)d_in[3];
    const float* kp    = (const float*)d_in[4];
    const float* vp    = (const float*)d_in[5];
    const float* Wc    = (const float*)d_in[6];
    const float* bc    = (const float*)d_in[7];
    float* logits = (float*)d_out;

    float* ws   = (float*)d_ws;
    float* qkv  = ws;                 // 3*784*12 = 28224 floats
    float* outb = ws + 28224;         // 4*2352   =  9408 floats

    qcirc_kernel<<<dim3(NPATCH, NB, 3), 64, 0, stream>>>(x, Wp, bproj, qp, kp, vp, qkv);
    attn_kernel <<<dim3(NPATCH, NB),   256, 0, stream>>>(qkv, outb);
    cls_kernel  <<<NCLS,               256, 0, stream>>>(outb, Wc, bc, logits);
}

// Round 6
// 125.616 us; speedup vs baseline: 1.0897x; 1.0897x over previous
//
#include <hip/hip_runtime.h>
#include <math.h>

// ---- Problem constants -----------------------------------------------------
#define NQ        12
#define NPS       14
#define NPATCH    196
#define NB        4
#define NCLS      1000
#define FEATDIM   2352           // 196*12
#define SCALE_F   0.28867513459481287f  // 1/sqrt(12)
#define LSTRIDE   33             // floats per thread region (32 amps + 1 pad)

// ---- Layouts ----------------------------------------------------------------
// 128-thread block (2 waves), 32 amps/thread: 5 state bits in registers (r),
// 7 in tid (t0..t5 lane bits, t6 wave bit). Position = 11 - qubit.
// PR[L][k] = state position of reg bit k; PT[L][k] = state position of tid bit k.
// All 6 relayout transitions verified conflict-free mod 32 (stride 33: lane-bit
// weights per transition = 5 distinct powers of two + one dup/zero => 2-way max).
constexpr int PR[6][5] = {
    {11,10, 9, 8, 7},   // L1: q0,q1,q2,q3,q4
    { 7, 6, 5, 4, 3},   // L2: q4,q5,q6,q7,q8
    { 3, 2, 1, 0,11},   // L3: q8,q9,q10,q11,q0
    {11,10, 7, 6, 3},   // L4: q0,q1,q4,q5,q8
    {10, 9, 5, 2, 1},   // L5: q1,q2,q6,q9,q10
    { 9, 8, 4, 1, 0},   // L6: q2,q3,q7,q10,q11
};
constexpr int PT[6][7] = {
    { 5, 4, 3, 1, 2, 0, 6},   // L1 tid: q6,q7,q8,q10,q9,q11 | wave q5
    {11,10, 2, 1, 9, 8, 0},   // L2 tid: q0,q1,q9,q10,q2,q3 | wave q11
    { 8, 7, 6, 9, 5, 4,10},   // L3 tid: q3,q4,q5,q2,q6,q7 | wave q1
    { 5, 8, 2, 1, 0, 4, 9},   // L4 tid: q6,q3,q9,q10,q11,q7 | wave q2
    {11, 7, 8, 4, 6, 3, 0},   // L5 tid: q0,q4,q3,q7,q5,q8 | wave q11
    { 5, 3,10, 7, 6, 2,11},   // L6 tid: q6,q8,q1,q4,q5,q9 | wave q0
};

// weight of state position `pos` in layout-X storage (addr = 33*t + r)
constexpr int wgt(int X, int pos) {
    for (int k = 0; k < 5; ++k) if (PR[X][k] == pos) return 1 << k;
    for (int k = 0; k < 7; ++k) if (PT[X][k] == pos) return LSTRIDE << k;
    return 0;
}
constexpr int rimm(int X, int Y, int r) {
    int s = 0;
    for (int j = 0; j < 5; ++j) if ((r >> j) & 1) s += wgt(X, PR[Y][j]);
    return s;
}

template<int X, int Y>
__device__ __forceinline__ void relayout(float amp[32], float* lds, int tid) {
    float* w = lds + LSTRIDE * tid;
    #pragma unroll
    for (int r = 0; r < 32; ++r) w[r] = amp[r];
    __syncthreads();
    int base = 0;
    #pragma unroll
    for (int j = 0; j < 7; ++j)
        base += ((tid >> j) & 1) ? wgt(X, PT[Y][j]) : 0;
    #pragma unroll
    for (int r = 0; r < 32; ++r)
        amp[r] = lds[base + rimm(X, Y, r)];
    __syncthreads();   // WAR guard before next relayout's writes
}

// RBS gate on register bits MI (first qubit w1) / MJ (second qubit w2).
// Half-angle form: gc = 0.5*cos(2t), gs = 0.5*sin(2t).
template<int MI, int MJ>
__device__ __forceinline__ void apply_gate(float amp[32], float gc, float gs) {
    #pragma unroll
    for (int m = 0; m < 32; ++m) {
        if (m & (MI | MJ)) continue;
        float a0 = amp[m], a1 = amp[m | MJ], a2 = amp[m | MI], a3 = amp[m | MI | MJ];
        float p  = a0 + a1, q  = a0 - a1;
        float p2 = a2 + a3, q2 = a2 - a3;
        float t1 = 0.5f * p  + gc * q  - gs * q2;
        float t2 = 0.5f * p2 + gc * q2 + gs * q;
        amp[m]           = t1;
        amp[m | MJ]      = p  - t1;
        amp[m | MI]      = t2;
        amp[m | MI | MJ] = p2 - t2;
    }
}

__device__ const int SLOT[12] = {0,3,7,8,4,5,1,9,2,6,10,11};

// ---- Kernel: fused projection + quantum circuit ----------------------------
// grid (196, 4, 3), block 128 (two waves).
__global__ __launch_bounds__(128, 4) void qcirc_kernel(
    const float* __restrict__ x,      // (4,3,224,224)
    const float* __restrict__ Wp,     // (12,256)
    const float* __restrict__ bproj,  // (12,)
    const float* __restrict__ qp,
    const float* __restrict__ kp,
    const float* __restrict__ vp,
    float* __restrict__ qkv)          // (3,784,12)
{
    __shared__ __align__(16) float lds[128 * LSTRIDE];
    __shared__ float chs[NQ], shs[NQ];
    __shared__ float gC[40], gS[40];
    __shared__ float red2[2][12];

    const int tid = threadIdx.x;
    const int p = blockIdx.x, b = blockIdx.y, c = blockIdx.z;
    const int bp = b * NPATCH + p;
    const float* params = (c == 0) ? qp : (c == 1) ? kp : vp;

    // ---- projection: 2 pixels/thread, 6-level butterfly + wave combine ----
    float part[NQ];
    #pragma unroll
    for (int q = 0; q < NQ; ++q) part[q] = 0.0f;
    {
        int py = p / NPS, px = p % NPS;
        const float* xb = x + (size_t)b * 3 * 224 * 224;
        #pragma unroll
        for (int k = 0; k < 2; ++k) {
            int pix = tid + 128 * k;
            int off = (py * 16 + (pix >> 4)) * 224 + px * 16 + (pix & 15);
            float v = (xb[off] + xb[off + 50176] + xb[off + 100352]) * (1.0f / 3.0f);
            #pragma unroll
            for (int q = 0; q < NQ; ++q) part[q] += v * Wp[q * 256 + pix];
        }
    }
    if (tid < 40) {
        int l = tid / 20, g = tid - l * 20;
        float th = params[l * 32 + g];
        gC[tid] = 0.5f * cosf(2.0f * th);
        gS[tid] = 0.5f * sinf(2.0f * th);
    }
    #pragma unroll
    for (int o = 1; o < 64; o <<= 1) {
        #pragma unroll
        for (int q = 0; q < NQ; ++q) part[q] += __shfl_xor(part[q], o);
    }
    {
        int lane = tid & 63, wv = tid >> 6;
        if (lane == 0) {
            #pragma unroll
            for (int q = 0; q < NQ; ++q) red2[wv][q] = part[q];
        }
    }
    __syncthreads();
    if (tid < NQ) {
        float h = 0.5f * (red2[0][tid] + red2[1][tid] + bproj[tid]);
        chs[tid] = cosf(h); shs[tid] = sinf(h);
    }
    __syncthreads();

    // ---- init in L1: reg b0..b4 = q0..q4; tid: t0=q6 t1=q7 t2=q8 t3=q10
    //      t4=q9 t5=q11 t6=q5 ----
    float amp[32];
    {
        float hi = ((tid &  1) ? shs[6]  : chs[6])  *
                   ((tid &  2) ? shs[7]  : chs[7])  *
                   ((tid &  4) ? shs[8]  : chs[8])  *
                   ((tid &  8) ? shs[10] : chs[10]) *
                   ((tid & 16) ? shs[9]  : chs[9])  *
                   ((tid & 32) ? shs[11] : chs[11]) *
                   ((tid & 64) ? shs[5]  : chs[5]);
        float pA[8], pB[4];
        #pragma unroll
        for (int i = 0; i < 8; ++i)
            pA[i] = ((i & 1) ? shs[0] : chs[0]) * ((i & 2) ? shs[1] : chs[1]) *
                    ((i & 4) ? shs[2] : chs[2]);
        #pragma unroll
        for (int i = 0; i < 4; ++i)
            pB[i] = ((i & 1) ? shs[3] : chs[3]) * ((i & 2) ? shs[4] : chs[4]);
        #pragma unroll
        for (int r = 0; r < 32; ++r) amp[r] = pA[r & 7] * pB[r >> 3] * hi;
    }

    // ---- 2 layers x 6 runs; 11 relayouts; dep-DAG-verified schedule ----
    #pragma unroll 1
    for (int l = 0; l < 2; ++l) {
        const int bb = l * 20;
        // R1 (L1: q0..q4): p0(0,1) p1(2,3) p6(0,2) p7(1,3)
        apply_gate<1, 2>(amp, gC[bb+0], gS[bb+0]);
        apply_gate<4, 8>(amp, gC[bb+1], gS[bb+1]);
        apply_gate<1, 4>(amp, gC[bb+6], gS[bb+6]);
        apply_gate<2, 8>(amp, gC[bb+7], gS[bb+7]);
        relayout<0,1>(amp, lds, tid);
        // R2 (L2: q4..q8): p2(4,5) p3(6,7) p8(4,6) p9(5,7)
        apply_gate<1, 2>(amp, gC[bb+2], gS[bb+2]);
        apply_gate<4, 8>(amp, gC[bb+3], gS[bb+3]);
        apply_gate<1, 4>(amp, gC[bb+8], gS[bb+8]);
        apply_gate<2, 8>(amp, gC[bb+9], gS[bb+9]);
        relayout<1,2>(amp, lds, tid);
        // R3 (L3: q8..q11,q0): p4(8,9) p5(10,11) p10(8,10) p11(9,11)
        apply_gate<1, 2>(amp, gC[bb+4],  gS[bb+4]);
        apply_gate<4, 8>(amp, gC[bb+5],  gS[bb+5]);
        apply_gate<1, 4>(amp, gC[bb+10], gS[bb+10]);
        apply_gate<2, 8>(amp, gC[bb+11], gS[bb+11]);
        relayout<2,3>(amp, lds, tid);
        // R4 (L4: q0,q1,q4,q5,q8): p12(0,4) p13(1,5) p16(0,8)
        apply_gate<1, 4>(amp, gC[bb+12], gS[bb+12]);
        apply_gate<2, 8>(amp, gC[bb+13], gS[bb+13]);
        apply_gate<1,16>(amp, gC[bb+16], gS[bb+16]);
        relayout<3,4>(amp, lds, tid);
        // R5 (L5: q1,q2,q6,q9,q10): p14(2,6) p17(1,9)
        apply_gate<2, 4>(amp, gC[bb+14], gS[bb+14]);
        apply_gate<1, 8>(amp, gC[bb+17], gS[bb+17]);
        relayout<4,5>(amp, lds, tid);
        // R6 (L6: q2,q3,q7,q10,q11): p15(3,7) p18(2,10) p19(3,11)
        apply_gate<2, 4>(amp, gC[bb+15], gS[bb+15]);
        apply_gate<1, 8>(amp, gC[bb+18], gS[bb+18]);
        apply_gate<2,16>(amp, gC[bb+19], gS[bb+19]);
        if (l == 0) relayout<5,0>(amp, lds, tid);
    }

    // ---- expvals in L6: reg b0=q2 b1=q3 b2=q7 b3=q10 b4=q11;
    //      tid: t0=q6 t1=q8 t2=q1 t3=q4 t4=q5 t5=q9 t6=q0 ----
    float T, Sq2, Sq3, Sq7, Sq10, Sq11;
    {
        float t1[16]; Sq2 = 0.0f;
        #pragma unroll
        for (int i = 0; i < 16; ++i) {
            float e = amp[2*i] * amp[2*i], o = amp[2*i+1] * amp[2*i+1];
            t1[i] = e + o; Sq2 += e - o;
        }
        float t2[8]; Sq3 = 0.0f;
        #pragma unroll
        for (int i = 0; i < 8; ++i) { t2[i] = t1[2*i] + t1[2*i+1]; Sq3 += t1[2*i] - t1[2*i+1]; }
        float t3[4]; Sq7 = 0.0f;
        #pragma unroll
        for (int i = 0; i < 4; ++i) { t3[i] = t2[2*i] + t2[2*i+1]; Sq7 += t2[2*i] - t2[2*i+1]; }
        float t4[2]; Sq10 = 0.0f;
        #pragma unroll
        for (int i = 0; i < 2; ++i) { t4[i] = t3[2*i] + t3[2*i+1]; Sq10 += t3[2*i] - t3[2*i+1]; }
        T = t4[0] + t4[1]; Sq11 = t4[0] - t4[1];
    }
    // signed butterfly over 6 lane bits
    float A = T, M[6];
    #pragma unroll
    for (int pbit = 0; pbit < 6; ++pbit) {
        int msk = 1 << pbit;
        float Ap = __shfl_xor(A, msk);
        float d  = A - Ap;
        M[pbit] = (tid & msk) ? -d : d;
        A += Ap;
        #pragma unroll
        for (int k = 0; k < 6; ++k)
            if (k < pbit) M[k] += __shfl_xor(M[k], msk);
        Sq2  += __shfl_xor(Sq2,  msk);
        Sq3  += __shfl_xor(Sq3,  msk);
        Sq7  += __shfl_xor(Sq7,  msk);
        Sq10 += __shfl_xor(Sq10, msk);
        Sq11 += __shfl_xor(Sq11, msk);
    }
    {
        int lane = tid & 63, wv = tid >> 6;
        if (lane == 0) {
            red2[wv][0] = A;                 // q0 carrier (wave-signed)
            red2[wv][1] = M[0];              // q6
            red2[wv][2] = M[1];              // q8
            red2[wv][3] = M[2];              // q1
            red2[wv][4] = M[3];              // q4
            red2[wv][5] = M[4];              // q5
            red2[wv][6] = M[5];              // q9
            red2[wv][7] = Sq2;  red2[wv][8]  = Sq3;
            red2[wv][9] = Sq7;  red2[wv][10] = Sq10; red2[wv][11] = Sq11;
        }
    }
    __syncthreads();
    if (tid < NQ) {
        int sl = SLOT[tid];
        float v0 = red2[0][sl], v1 = red2[1][sl];
        float s = (tid == 0) ? (v0 - v1) : (v0 + v1);
        qkv[((size_t)c * (NB * NPATCH) + bp) * NQ + tid] = s;
    }
}

// ---- Kernel: attention ------------------------------------------------------
__global__ __launch_bounds__(256) void attn_kernel(
    const float* __restrict__ qkv,    // (3,784,12)
    float* __restrict__ outb)         // (4,2352)
{
    int tid = threadIdx.x;
    int qp = blockIdx.x, b = blockIdx.y;
    const float* Q = qkv;
    const float* K = qkv + NB * NPATCH * NQ;
    const float* V = qkv + 2 * NB * NPATCH * NQ;

    __shared__ float redm[4], reds[4], redv[4][NQ];

    float4 q0 = ((const float4*)(Q + (b * NPATCH + qp) * NQ))[0];
    float4 q1 = ((const float4*)(Q + (b * NPATCH + qp) * NQ))[1];
    float4 q2 = ((const float4*)(Q + (b * NPATCH + qp) * NQ))[2];

    float score = -1e30f;
    float4 v0, v1, v2;
    if (tid < NPATCH) {
        const float4* K4 = (const float4*)(K + (b * NPATCH + tid) * NQ);
        float4 k0 = K4[0], k1 = K4[1], k2 = K4[2];
        float s = q0.x*k0.x + q0.y*k0.y + q0.z*k0.z + q0.w*k0.w
                + q1.x*k1.x + q1.y*k1.y + q1.z*k1.z + q1.w*k1.w
                + q2.x*k2.x + q2.y*k2.y + q2.z*k2.z + q2.w*k2.w;
        score = s * SCALE_F;
        const float4* V4 = (const float4*)(V + (b * NPATCH + tid) * NQ);
        v0 = V4[0]; v1 = V4[1]; v2 = V4[2];
    }
    float m = score;
    #pragma unroll
    for (int o = 32; o > 0; o >>= 1) m = fmaxf(m, __shfl_down(m, o));
    int lane = tid & 63, wv = tid >> 6;
    if (lane == 0) redm[wv] = m;
    __syncthreads();
    float maxv = fmaxf(fmaxf(redm[0], redm[1]), fmaxf(redm[2], redm[3]));

    float w = (tid < NPATCH) ? expf(score - maxv) : 0.0f;
    float sm = w;
    #pragma unroll
    for (int o = 32; o > 0; o >>= 1) sm += __shfl_down(sm, o);
    if (lane == 0) reds[wv] = sm;

    float part[NQ];
    #pragma unroll
    for (int d = 0; d < NQ; d++) part[d] = 0.0f;
    if (tid < NPATCH) {
        part[0] = w*v0.x; part[1] = w*v0.y; part[2]  = w*v0.z; part[3]  = w*v0.w;
        part[4] = w*v1.x; part[5] = w*v1.y; part[6]  = w*v1.z; part[7]  = w*v1.w;
        part[8] = w*v2.x; part[9] = w*v2.y; part[10] = w*v2.z; part[11] = w*v2.w;
    }
    #pragma unroll
    for (int d = 0; d < NQ; d++) {
        #pragma unroll
        for (int o = 32; o > 0; o >>= 1) part[d] += __shfl_down(part[d], o);
    }
    if (lane == 0) {
        #pragma unroll
        for (int d = 0; d < NQ; d++) redv[wv][d] = part[d];
    }
    __syncthreads();
    if (tid < NQ) {
        float sumv = reds[0] + reds[1] + reds[2] + reds[3];
        float s = redv[0][tid] + redv[1][tid] + redv[2][tid] + redv[3][tid];
        outb[(size_t)b * FEATDIM + qp * NQ + tid] = s / sumv;
    }
}

// ---- Kernel: classifier -----------------------------------------------------
__global__ __launch_bounds__(256) void cls_kernel(
    const float* __restrict__ outb,   // (4,2352)
    const float* __restrict__ Wc,     // (1000,2352)
    const float* __restrict__ bc,     // (1000,)
    float* __restrict__ logits)       // (4,1000)
{
    int o = blockIdx.x, tid = threadIdx.x;
    float acc[NB] = {0.0f, 0.0f, 0.0f, 0.0f};
    const float4* w4 = (const float4*)(Wc + (size_t)o * FEATDIM);
    for (int j = tid; j < FEATDIM / 4; j += 256) {
        float4 w = w4[j];
        #pragma unroll
        for (int b = 0; b < NB; b++) {
            float4 ov = ((const float4*)(outb + (size_t)b * FEATDIM))[j];
            acc[b] += w.x*ov.x + w.y*ov.y + w.z*ov.z + w.w*ov.w;
        }
    }
    #pragma unroll
    for (int b = 0; b < NB; b++) {
        #pragma unroll
        for (int off = 32; off > 0; off >>= 1) acc[b] += __shfl_down(acc[b], off);
    }
    __shared__ float red[4][NB];
    int lane = tid & 63, wv = tid >> 6;
    if (lane == 0) {
        #pragma unroll
        for (int b = 0; b < NB; b++) red[wv][b] = acc[b];
    }
    __syncthreads();
    if (tid < NB) {
        float s = red[0][tid] + red[1][tid] + red[2][tid] + red[3][tid];
        logits[(size_t)tid * NCLS + o] = s + bc[o];
    }
}

// ---- Launch ----------------------------------------------------------------
extern "C" void kernel_launch(void* const* d_in, const int* in_sizes, int n_in,
                              void* d_out, int out_size, void* d_ws, size_t ws_size,
                              hipStream_t stream) {
    const float* x     = (const float*)d_in[0];
    const float* Wp    = (const float*)d_in[1];
    const float* bproj = (const float*)d_in[2];
    const float* qp    = (const float*)d_in[3];
    const float* kp    = (const float*)d_in[4];
    const float* vp    = (const float*)d_in[5];
    const float* Wc    = (const float*)d_in[6];
    const float* bc    = (const float*)d_in[7];
    float* logits = (float*)d_out;

    float* ws   = (float*)d_ws;
    float* qkv  = ws;                 // 3*784*12 = 28224 floats
    float* outb = ws + 28224;         // 4*2352   =  9408 floats

    qcirc_kernel<<<dim3(NPATCH, NB, 3), 128, 0, stream>>>(x, Wp, bproj, qp, kp, vp, qkv);
    attn_kernel <<<dim3(NPATCH, NB),    256, 0, stream>>>(qkv, outb);
    cls_kernel  <<<NCLS,                256, 0, stream>>>(outb, Wc, bc, logits);
}

// Round 7
// 125.028 us; speedup vs baseline: 1.0948x; 1.0047x over previous
//
#include <hip/hip_runtime.h>
#include <math.h>

// ---- Problem constants -----------------------------------------------------
#define NQ        12
#define NPS       14
#define NPATCH    196
#define NB        4
#define NCLS      1000
#define FEATDIM   2352           // 196*12
#define SCALE_F   0.28867513459481287f  // 1/sqrt(12)

// ---- Layouts ----------------------------------------------------------------
// 128-thread block (2 waves), 32 amps/thread: 5 state bits in registers,
// 7 in tid (t0..t5 lane, t6 wave). Position = 11 - qubit.
// PR[L][k] = state position of reg bit k. PT[L][m] = state position of tid bit m.
// Relayouts go through an 8.5KB stride-17 buffer in two 16-amp half-passes,
// split on a state bit register-resident in both layouts. All 6 transitions
// verified conflict-free (uniform 2 lanes/bank) by mod-32 GF analysis.
constexpr int PRa[6][5] = {
    {11,10, 9, 8, 7},   // L1: q0,q1,q2,q3,q4
    { 7, 6, 5, 4, 3},   // L2: q4,q5,q6,q7,q8
    { 3, 2, 1, 0,11},   // L3: q8,q9,q10,q11,q0
    {11,10, 7, 6, 3},   // L4: q0,q1,q4,q5,q8
    {10, 9, 5, 2, 1},   // L5: q1,q2,q6,q9,q10
    { 9, 8, 4, 1, 0},   // L6: q2,q3,q7,q10,q11
};
constexpr int PTa[6][7] = {
    { 6, 5, 4, 3, 1, 0, 2},   // L1 tid: q5,q6,q7,q8,q10,q11 | wave q9
    {11,10, 1, 0, 9, 8, 2},   // L2 tid: q0,q1,q10,q11,q2,q3 | wave q9
    { 8, 9, 7, 6, 5, 4,10},   // L3 tid: q3,q2,q4,q5,q6,q7 | wave q1
    { 8, 5, 2, 1, 0, 4, 9},   // L4 tid: q3,q6,q9,q10,q11,q7 | wave q2
    { 7, 4, 0,11, 6, 3, 8},   // L5 tid: q4,q7,q11,q0,q5,q8 | wave q3
    { 6,11,10, 2, 5, 3, 7},   // L6 tid: q5,q0,q1,q9,q6,q8 | wave q4
};
// transition i: layout i -> (i+1)%6; split reg-bit indices (shared qubit)
constexpr int IXa[6] = {4,4,4,1,1,0};
constexpr int IYa[6] = {0,0,0,0,0,2};

// weight of state position `pos` in X's compacted half-pass storage
// (addr = 17*t + compact(r)); split bit excluded (constant within a pass).
constexpr int cwgt(int X, int IX, int pos) {
    for (int k = 0; k < 5; ++k)
        if (PRa[X][k] == pos) return (k == IX) ? 0 : (1 << (k - (k > IX ? 1 : 0)));
    for (int m = 0; m < 7; ++m)
        if (PTa[X][m] == pos) return 17 << m;
    return 0;
}
// imm offset for reader compact reg rc (4 bits, Y reg bits skipping IY)
constexpr int rimm2(int X, int IX, int Y, int IY, int rc) {
    int s = 0;
    for (int j = 0; j < 4; ++j)
        if ((rc >> j) & 1) s += cwgt(X, IX, PRa[Y][j + (j >= IY ? 1 : 0)]);
    return s;
}

template<int TI>
__device__ __forceinline__ void relayout2(float amp[32], float* lds, int tid) {
    constexpr int X = TI, Y = (TI + 1) % 6;
    constexpr int IX = IXa[TI], IY = IYa[TI];
    float tmp[16];
    // pass 0: state elements with split bit = 0
    #pragma unroll
    for (int rc = 0; rc < 16; ++rc) {
        int r = (rc & ((1 << IX) - 1)) | ((rc >> IX) << (IX + 1));
        lds[17 * tid + rc] = amp[r];
    }
    __syncthreads();
    int base = 0;
    #pragma unroll
    for (int j = 0; j < 7; ++j)
        base += ((tid >> j) & 1) ? cwgt(X, IX, PTa[Y][j]) : 0;
    #pragma unroll
    for (int rc = 0; rc < 16; ++rc)
        tmp[rc] = lds[base + rimm2(X, IX, Y, IY, rc)];
    __syncthreads();
    // pass 1: split bit = 1 (original amp regs with bit IX=1 still intact)
    #pragma unroll
    for (int rc = 0; rc < 16; ++rc) {
        int r = (rc & ((1 << IX) - 1)) | ((rc >> IX) << (IX + 1)) | (1 << IX);
        lds[17 * tid + rc] = amp[r];
    }
    __syncthreads();
    #pragma unroll
    for (int rc = 0; rc < 16; ++rc) {
        int r = (rc & ((1 << IY) - 1)) | ((rc >> IY) << (IY + 1)) | (1 << IY);
        amp[r] = lds[base + rimm2(X, IX, Y, IY, rc)];
    }
    __syncthreads();
    #pragma unroll
    for (int rc = 0; rc < 16; ++rc) {
        int r = (rc & ((1 << IY) - 1)) | ((rc >> IY) << (IY + 1));
        amp[r] = tmp[rc];
    }
}

// RBS gate on register bits MI (first qubit w1) / MJ (second qubit w2).
// Half-angle form: gc = 0.5*cos(2t), gs = 0.5*sin(2t).
template<int MI, int MJ>
__device__ __forceinline__ void apply_gate(float amp[32], float gc, float gs) {
    #pragma unroll
    for (int m = 0; m < 32; ++m) {
        if (m & (MI | MJ)) continue;
        float a0 = amp[m], a1 = amp[m | MJ], a2 = amp[m | MI], a3 = amp[m | MI | MJ];
        float p  = a0 + a1, q  = a0 - a1;
        float p2 = a2 + a3, q2 = a2 - a3;
        float t1 = 0.5f * p  + gc * q  - gs * q2;
        float t2 = 0.5f * p2 + gc * q2 + gs * q;
        amp[m]           = t1;
        amp[m | MJ]      = p  - t1;
        amp[m | MI]      = t2;
        amp[m | MI | MJ] = p2 - t2;
    }
}

// output slot per qubit: red2 slots {A, M0..M5, Sq2, Sq3, Sq7, Sq10, Sq11}
// L6 butterfly M[m] <-> qubits [q5,q0,q1,q9,q6,q8]; wave bit = q4.
__device__ const int SLOT[12] = {2,3,7,8,0,1,5,9,6,4,10,11};

// ---- Kernel: fused projection + quantum circuit ----------------------------
// grid (196, 4, 3), block 128 (two waves). LDS 9216 B -> 10+ blocks/CU.
__global__ __launch_bounds__(128, 5) void qcirc_kernel(
    const float* __restrict__ x,      // (4,3,224,224)
    const float* __restrict__ Wp,     // (12,256)
    const float* __restrict__ bproj,  // (12,)
    const float* __restrict__ qp,
    const float* __restrict__ kp,
    const float* __restrict__ vp,
    float* __restrict__ qkv)          // (3,784,12)
{
    __shared__ __align__(16) float lds[2176];   // 17*127+16 words
    __shared__ float chs[NQ], shs[NQ];
    __shared__ float gC[40], gS[40];
    __shared__ float red2[2][12];

    const int tid = threadIdx.x;
    const int p = blockIdx.x, b = blockIdx.y, c = blockIdx.z;
    const int bp = b * NPATCH + p;
    const float* params = (c == 0) ? qp : (c == 1) ? kp : vp;

    // ---- projection: 2 pixels/thread, butterfly + wave combine ----
    float part[NQ];
    #pragma unroll
    for (int q = 0; q < NQ; ++q) part[q] = 0.0f;
    {
        int py = p / NPS, px = p % NPS;
        const float* xb = x + (size_t)b * 3 * 224 * 224;
        #pragma unroll
        for (int k = 0; k < 2; ++k) {
            int pix = tid + 128 * k;
            int off = (py * 16 + (pix >> 4)) * 224 + px * 16 + (pix & 15);
            float v = (xb[off] + xb[off + 50176] + xb[off + 100352]) * (1.0f / 3.0f);
            #pragma unroll
            for (int q = 0; q < NQ; ++q) part[q] += v * Wp[q * 256 + pix];
        }
    }
    if (tid < 40) {
        int l = tid / 20, g = tid - l * 20;
        float th = params[l * 32 + g];
        gC[tid] = 0.5f * cosf(2.0f * th);
        gS[tid] = 0.5f * sinf(2.0f * th);
    }
    #pragma unroll
    for (int o = 1; o < 64; o <<= 1) {
        #pragma unroll
        for (int q = 0; q < NQ; ++q) part[q] += __shfl_xor(part[q], o);
    }
    {
        int lane = tid & 63, wv = tid >> 6;
        if (lane == 0) {
            #pragma unroll
            for (int q = 0; q < NQ; ++q) red2[wv][q] = part[q];
        }
    }
    __syncthreads();
    if (tid < NQ) {
        float h = 0.5f * (red2[0][tid] + red2[1][tid] + bproj[tid]);
        chs[tid] = cosf(h); shs[tid] = sinf(h);
    }
    __syncthreads();

    // ---- init in L1: reg b0..b4 = q0..q4; tid m0..m6 = q5,q6,q7,q8,q10,q11|q9
    float amp[32];
    {
        float hi = ((tid &  1) ? shs[5]  : chs[5])  *
                   ((tid &  2) ? shs[6]  : chs[6])  *
                   ((tid &  4) ? shs[7]  : chs[7])  *
                   ((tid &  8) ? shs[8]  : chs[8])  *
                   ((tid & 16) ? shs[10] : chs[10]) *
                   ((tid & 32) ? shs[11] : chs[11]) *
                   ((tid & 64) ? shs[9]  : chs[9]);
        float pA[8], pB[4];
        #pragma unroll
        for (int i = 0; i < 8; ++i)
            pA[i] = ((i & 1) ? shs[0] : chs[0]) * ((i & 2) ? shs[1] : chs[1]) *
                    ((i & 4) ? shs[2] : chs[2]);
        #pragma unroll
        for (int i = 0; i < 4; ++i)
            pB[i] = ((i & 1) ? shs[3] : chs[3]) * ((i & 2) ? shs[4] : chs[4]);
        #pragma unroll
        for (int r = 0; r < 32; ++r) amp[r] = pA[r & 7] * pB[r >> 3] * hi;
    }

    // ---- 2 layers x 6 runs; 11 relayouts; schedule identical to verified r5 ----
    #pragma unroll 1
    for (int l = 0; l < 2; ++l) {
        const int bb = l * 20;
        // R1 (L1: q0..q4): p0(0,1) p1(2,3) p6(0,2) p7(1,3)
        apply_gate<1, 2>(amp, gC[bb+0], gS[bb+0]);
        apply_gate<4, 8>(amp, gC[bb+1], gS[bb+1]);
        apply_gate<1, 4>(amp, gC[bb+6], gS[bb+6]);
        apply_gate<2, 8>(amp, gC[bb+7], gS[bb+7]);
        relayout2<0>(amp, lds, tid);
        // R2 (L2: q4..q8): p2(4,5) p3(6,7) p8(4,6) p9(5,7)
        apply_gate<1, 2>(amp, gC[bb+2], gS[bb+2]);
        apply_gate<4, 8>(amp, gC[bb+3], gS[bb+3]);
        apply_gate<1, 4>(amp, gC[bb+8], gS[bb+8]);
        apply_gate<2, 8>(amp, gC[bb+9], gS[bb+9]);
        relayout2<1>(amp, lds, tid);
        // R3 (L3: q8..q11,q0): p4(8,9) p5(10,11) p10(8,10) p11(9,11)
        apply_gate<1, 2>(amp, gC[bb+4],  gS[bb+4]);
        apply_gate<4, 8>(amp, gC[bb+5],  gS[bb+5]);
        apply_gate<1, 4>(amp, gC[bb+10], gS[bb+10]);
        apply_gate<2, 8>(amp, gC[bb+11], gS[bb+11]);
        relayout2<2>(amp, lds, tid);
        // R4 (L4: q0,q1,q4,q5,q8): p12(0,4) p13(1,5) p16(0,8)
        apply_gate<1, 4>(amp, gC[bb+12], gS[bb+12]);
        apply_gate<2, 8>(amp, gC[bb+13], gS[bb+13]);
        apply_gate<1,16>(amp, gC[bb+16], gS[bb+16]);
        relayout2<3>(amp, lds, tid);
        // R5 (L5: q1,q2,q6,q9,q10): p14(2,6) p17(1,9)
        apply_gate<2, 4>(amp, gC[bb+14], gS[bb+14]);
        apply_gate<1, 8>(amp, gC[bb+17], gS[bb+17]);
        relayout2<4>(amp, lds, tid);
        // R6 (L6: q2,q3,q7,q10,q11): p15(3,7) p18(2,10) p19(3,11)
        apply_gate<2, 4>(amp, gC[bb+15], gS[bb+15]);
        apply_gate<1, 8>(amp, gC[bb+18], gS[bb+18]);
        apply_gate<2,16>(amp, gC[bb+19], gS[bb+19]);
        if (l == 0) relayout2<5>(amp, lds, tid);
    }

    // ---- expvals in L6: reg b0=q2 b1=q3 b2=q7 b3=q10 b4=q11;
    //      tid m0..m5 = q5,q0,q1,q9,q6,q8; wave = q4 ----
    float T, Sq2, Sq3, Sq7, Sq10, Sq11;
    {
        float t1[16]; Sq2 = 0.0f;
        #pragma unroll
        for (int i = 0; i < 16; ++i) {
            float e = amp[2*i] * amp[2*i], o = amp[2*i+1] * amp[2*i+1];
            t1[i] = e + o; Sq2 += e - o;
        }
        float t2[8]; Sq3 = 0.0f;
        #pragma unroll
        for (int i = 0; i < 8; ++i) { t2[i] = t1[2*i] + t1[2*i+1]; Sq3 += t1[2*i] - t1[2*i+1]; }
        float t3[4]; Sq7 = 0.0f;
        #pragma unroll
        for (int i = 0; i < 4; ++i) { t3[i] = t2[2*i] + t2[2*i+1]; Sq7 += t2[2*i] - t2[2*i+1]; }
        float t4[2]; Sq10 = 0.0f;
        #pragma unroll
        for (int i = 0; i < 2; ++i) { t4[i] = t3[2*i] + t3[2*i+1]; Sq10 += t3[2*i] - t3[2*i+1]; }
        T = t4[0] + t4[1]; Sq11 = t4[0] - t4[1];
    }
    float A = T, M[6];
    #pragma unroll
    for (int pbit = 0; pbit < 6; ++pbit) {
        int msk = 1 << pbit;
        float Ap = __shfl_xor(A, msk);
        float d  = A - Ap;
        M[pbit] = (tid & msk) ? -d : d;
        A += Ap;
        #pragma unroll
        for (int k = 0; k < 6; ++k)
            if (k < pbit) M[k] += __shfl_xor(M[k], msk);
        Sq2  += __shfl_xor(Sq2,  msk);
        Sq3  += __shfl_xor(Sq3,  msk);
        Sq7  += __shfl_xor(Sq7,  msk);
        Sq10 += __shfl_xor(Sq10, msk);
        Sq11 += __shfl_xor(Sq11, msk);
    }
    {
        int lane = tid & 63, wv = tid >> 6;
        if (lane == 0) {
            red2[wv][0] = A;
            red2[wv][1] = M[0]; red2[wv][2] = M[1]; red2[wv][3] = M[2];
            red2[wv][4] = M[3]; red2[wv][5] = M[4]; red2[wv][6] = M[5];
            red2[wv][7] = Sq2;  red2[wv][8]  = Sq3;
            red2[wv][9] = Sq7;  red2[wv][10] = Sq10; red2[wv][11] = Sq11;
        }
    }
    __syncthreads();
    if (tid < NQ) {
        int sl = SLOT[tid];
        float v0 = red2[0][sl], v1 = red2[1][sl];
        float s = (tid == 4) ? (v0 - v1) : (v0 + v1);   // wave bit = q4
        qkv[((size_t)c * (NB * NPATCH) + bp) * NQ + tid] = s;
    }
}

// ---- Kernel: attention ------------------------------------------------------
__global__ __launch_bounds__(256) void attn_kernel(
    const float* __restrict__ qkv,    // (3,784,12)
    float* __restrict__ outb)         // (4,2352)
{
    int tid = threadIdx.x;
    int qp = blockIdx.x, b = blockIdx.y;
    const float* Q = qkv;
    const float* K = qkv + NB * NPATCH * NQ;
    const float* V = qkv + 2 * NB * NPATCH * NQ;

    __shared__ float redm[4], reds[4], redv[4][NQ];

    float4 q0 = ((const float4*)(Q + (b * NPATCH + qp) * NQ))[0];
    float4 q1 = ((const float4*)(Q + (b * NPATCH + qp) * NQ))[1];
    float4 q2 = ((const float4*)(Q + (b * NPATCH + qp) * NQ))[2];

    float score = -1e30f;
    float4 v0, v1, v2;
    if (tid < NPATCH) {
        const float4* K4 = (const float4*)(K + (b * NPATCH + tid) * NQ);
        float4 k0 = K4[0], k1 = K4[1], k2 = K4[2];
        float s = q0.x*k0.x + q0.y*k0.y + q0.z*k0.z + q0.w*k0.w
                + q1.x*k1.x + q1.y*k1.y + q1.z*k1.z + q1.w*k1.w
                + q2.x*k2.x + q2.y*k2.y + q2.z*k2.z + q2.w*k2.w;
        score = s * SCALE_F;
        const float4* V4 = (const float4*)(V + (b * NPATCH + tid) * NQ);
        v0 = V4[0]; v1 = V4[1]; v2 = V4[2];
    }
    float m = score;
    #pragma unroll
    for (int o = 32; o > 0; o >>= 1) m = fmaxf(m, __shfl_down(m, o));
    int lane = tid & 63, wv = tid >> 6;
    if (lane == 0) redm[wv] = m;
    __syncthreads();
    float maxv = fmaxf(fmaxf(redm[0], redm[1]), fmaxf(redm[2], redm[3]));

    float w = (tid < NPATCH) ? expf(score - maxv) : 0.0f;
    float sm = w;
    #pragma unroll
    for (int o = 32; o > 0; o >>= 1) sm += __shfl_down(sm, o);
    if (lane == 0) reds[wv] = sm;

    float part[NQ];
    #pragma unroll
    for (int d = 0; d < NQ; d++) part[d] = 0.0f;
    if (tid < NPATCH) {
        part[0] = w*v0.x; part[1] = w*v0.y; part[2]  = w*v0.z; part[3]  = w*v0.w;
        part[4] = w*v1.x; part[5] = w*v1.y; part[6]  = w*v1.z; part[7]  = w*v1.w;
        part[8] = w*v2.x; part[9] = w*v2.y; part[10] = w*v2.z; part[11] = w*v2.w;
    }
    #pragma unroll
    for (int d = 0; d < NQ; d++) {
        #pragma unroll
        for (int o = 32; o > 0; o >>= 1) part[d] += __shfl_down(part[d], o);
    }
    if (lane == 0) {
        #pragma unroll
        for (int d = 0; d < NQ; d++) redv[wv][d] = part[d];
    }
    __syncthreads();
    if (tid < NQ) {
        float sumv = reds[0] + reds[1] + reds[2] + reds[3];
        float s = redv[0][tid] + redv[1][tid] + redv[2][tid] + redv[3][tid];
        outb[(size_t)b * FEATDIM + qp * NQ + tid] = s / sumv;
    }
}

// ---- Kernel: classifier -----------------------------------------------------
__global__ __launch_bounds__(256) void cls_kernel(
    const float* __restrict__ outb,   // (4,2352)
    const float* __restrict__ Wc,     // (1000,2352)
    const float* __restrict__ bc,     // (1000,)
    float* __restrict__ logits)       // (4,1000)
{
    int o = blockIdx.x, tid = threadIdx.x;
    float acc[NB] = {0.0f, 0.0f, 0.0f, 0.0f};
    const float4* w4 = (const float4*)(Wc + (size_t)o * FEATDIM);
    for (int j = tid; j < FEATDIM / 4; j += 256) {
        float4 w = w4[j];
        #pragma unroll
        for (int b = 0; b < NB; b++) {
            float4 ov = ((const float4*)(outb + (size_t)b * FEATDIM))[j];
            acc[b] += w.x*ov.x + w.y*ov.y + w.z*ov.z + w.w*ov.w;
        }
    }
    #pragma unroll
    for (int b = 0; b < NB; b++) {
        #pragma unroll
        for (int off = 32; off > 0; off >>= 1) acc[b] += __shfl_down(acc[b], off);
    }
    __shared__ float red[4][NB];
    int lane = tid & 63, wv = tid >> 6;
    if (lane == 0) {
        #pragma unroll
        for (int b = 0; b < NB; b++) red[wv][b] = acc[b];
    }
    __syncthreads();
    if (tid < NB) {
        float s = red[0][tid] + red[1][tid] + red[2][tid] + red[3][tid];
        logits[(size_t)tid * NCLS + o] = s + bc[o];
    }
}

// ---- Launch ----------------------------------------------------------------
extern "C" void kernel_launch(void* const* d_in, const int* in_sizes, int n_in,
                              void* d_out, int out_size, void* d_ws, size_t ws_size,
                              hipStream_t stream) {
    const float* x     = (const float*)d_in[0];
    const float* Wp    = (const float*)d_in[1];
    const float* bproj = (const float*)d_in[2];
    const float* qp    = (const float*)d_in[3];
    const float* kp    = (const float*)d_in[4];
    const float* vp    = (const float*)d_in[5];
    const float* Wc    = (const float*)d_in[6];
    const float* bc    = (const float*)d_in[7];
    float* logits = (float*)d_out;

    float* ws   = (float*)d_ws;
    float* qkv  = ws;                 // 3*784*12 = 28224 floats
    float* outb = ws + 28224;         // 4*2352   =  9408 floats

    qcirc_kernel<<<dim3(NPATCH, NB, 3), 128, 0, stream>>>(x, Wp, bproj, qp, kp, vp, qkv);
    attn_kernel <<<dim3(NPATCH, NB),    256, 0, stream>>>(qkv, outb);
    cls_kernel  <<<NCLS,                256, 0, stream>>>(outb, Wc, bc, logits);
}

// Round 8
// 120.193 us; speedup vs baseline: 1.1388x; 1.0402x over previous
//
#include <hip/hip_runtime.h>
#include <math.h>

// ---- Problem constants -----------------------------------------------------
#define NQ        12
#define NPS       14
#define NPATCH    196
#define NB        4
#define NCLS      1000
#define FEATDIM   2352           // 196*12
#define SCALE_F   0.28867513459481287f  // 1/sqrt(12)

// ---- Layouts ----------------------------------------------------------------
// 128-thread block (2 waves), 32 amps/thread: 5 state bits in registers,
// 7 in tid (m0..m5 lane, m6 wave). Split bit is ALWAYS amp bit 4 (IX=4).
// PRa[L][k] = qubit at amp bit k; PTa[L][m] = qubit at tid bit m (m6 = wave).
// Waves: L1,L2,L6 = q9; L3,L4,L5 = q3. Barriers only at T23 (9->3) and
// T56 (3->9); the other transitions keep the wave qubit => intra-wave,
// no __syncthreads (s_waitcnt lgkmcnt(0) only). All 6 transitions verified:
// reader lane-bit weights distinct mod 32 (stride 17) => max 2 lanes/bank.
constexpr int PRa[6][5] = {
    { 0, 1, 2, 3, 4},   // L1
    { 4, 5, 6, 7, 8},   // L2
    { 9,10,11, 0, 8},   // L3
    { 0, 4, 5, 8, 1},   // L4
    { 1, 6, 9,10, 2},   // L5
    { 7,10,11, 2, 3},   // L6
};
constexpr int PTa[6][7] = {
    {10, 5, 6, 7,11, 8, 9},   // L1
    { 1, 0, 3,10, 2,11, 9},   // L2
    { 2, 1, 4, 6, 7, 5, 3},   // L3
    { 7, 2, 6, 9,11,10, 3},   // L4
    { 0, 7, 4, 5, 8,11, 3},   // L5
    { 5, 0, 1, 6, 8, 4, 9},   // L6
};
// transition TI: layout TI -> (TI+1)%6. IY = amp-bit of split in Y. Barrier?
constexpr int  IYa[6]  = {0, 4, 3, 0, 3, 3};
constexpr bool BARa[6] = {false, true, false, false, true, false};

// weight (in floats) of qubit q in X's storage (addr = 17*t + rc, compact=b0..b3)
constexpr int cwgt(int X, int q) {
    for (int k = 0; k < 4; ++k) if (PRa[X][k] == q) return 1 << k;
    for (int m = 0; m < 7; ++m) if (PTa[X][m] == q) return 17 << m;
    return 0;  // split qubit: never queried
}
constexpr int rimm3(int X, int Y, int IY, int rc) {
    int s = 0;
    for (int j = 0; j < 4; ++j)
        if ((rc >> j) & 1) s += cwgt(X, PRa[Y][j + (j >= IY ? 1 : 0)]);
    return s;
}
constexpr int expand(int rc, int IY) {
    return (rc & ((1 << IY) - 1)) | ((rc >> IY) << (IY + 1));
}

__device__ __forceinline__ void wait_lgkm() {
    __asm__ __volatile__("s_waitcnt lgkmcnt(0)" ::: "memory");
}

template<int TI>
__device__ __forceinline__ void relayout3(float amp[32], float* lds, int tid) {
    constexpr int X = TI, Y = (TI + 1) % 6, IY = IYa[TI];
    constexpr bool BAR = BARa[TI];
    float* w = lds + 17 * tid;
    // pass 0: write old amp[0..15] (split bit b4 = 0)
    #pragma unroll
    for (int rc = 0; rc < 16; ++rc) w[rc] = amp[rc];
    if (BAR) __syncthreads(); else wait_lgkm();
    int base = 0;
    #pragma unroll
    for (int j = 0; j < 7; ++j)
        base += ((tid >> j) & 1) ? cwgt(X, PTa[Y][j]) : 0;
    float tmp[16];
    #pragma unroll
    for (int rc = 0; rc < 16; ++rc)
        tmp[rc] = lds[base + rimm3(X, Y, IY, rc)];
    if (BAR) __syncthreads(); else wait_lgkm();
    // pass 1: write old amp[16..31] (split bit b4 = 1)
    #pragma unroll
    for (int rc = 0; rc < 16; ++rc) w[rc] = amp[16 + rc];
    if (BAR) __syncthreads(); else wait_lgkm();
    #pragma unroll
    for (int rc = 0; rc < 16; ++rc)
        amp[expand(rc, IY) | (1 << IY)] = lds[base + rimm3(X, Y, IY, rc)];
    if (BAR) __syncthreads();   // protect next writes from cross-wave readers
    #pragma unroll
    for (int rc = 0; rc < 16; ++rc) amp[expand(rc, IY)] = tmp[rc];
}

// RBS gate on amp bits MI (first qubit w1) / MJ (second qubit w2).
// Half-angle form: gc = 0.5*cos(2t), gs = 0.5*sin(2t).
template<int MI, int MJ>
__device__ __forceinline__ void apply_gate(float amp[32], float gc, float gs) {
    #pragma unroll
    for (int m = 0; m < 32; ++m) {
        if (m & (MI | MJ)) continue;
        float a0 = amp[m], a1 = amp[m | MJ], a2 = amp[m | MI], a3 = amp[m | MI | MJ];
        float p  = a0 + a1, q  = a0 - a1;
        float p2 = a2 + a3, q2 = a2 - a3;
        float t1 = 0.5f * p  + gc * q  - gs * q2;
        float t2 = 0.5f * p2 + gc * q2 + gs * q;
        amp[m]           = t1;
        amp[m | MJ]      = p  - t1;
        amp[m | MI]      = t2;
        amp[m | MI | MJ] = p2 - t2;
    }
}

// ---- DPP wave-wide sum (result valid in lane 63), pure VALU ----------------
template<int CTRL>
__device__ __forceinline__ float dppadd(float x) {
    int s = __builtin_amdgcn_update_dpp(0, __float_as_int(x), CTRL, 0xf, 0xf, true);
    return x + __int_as_float(s);
}
__device__ __forceinline__ float wave_sum(float x) {
    x = dppadd<0x111>(x);   // row_shr:1
    x = dppadd<0x112>(x);   // row_shr:2
    x = dppadd<0x114>(x);   // row_shr:4
    x = dppadd<0x118>(x);   // row_shr:8
    x = dppadd<0x142>(x);   // row_bcast:15
    x = dppadd<0x143>(x);   // row_bcast:31
    return x;
}

// ---- Kernel: fused projection + quantum circuit ----------------------------
// grid (196, 4, 3), block 128 (two waves). LDS ~9.2 KB.
__global__ __launch_bounds__(128, 4) void qcirc_kernel(
    const float* __restrict__ x,      // (4,3,224,224)
    const float* __restrict__ Wp,     // (12,256)
    const float* __restrict__ bproj,  // (12,)
    const float* __restrict__ qp,
    const float* __restrict__ kp,
    const float* __restrict__ vp,
    float* __restrict__ qkv)          // (3,784,12)
{
    __shared__ __align__(16) float lds[2176];   // 17*128
    __shared__ float chs[NQ], shs[NQ];
    __shared__ float gC[40], gS[40];
    __shared__ float red2[2][12];

    const int tid = threadIdx.x;
    const int p = blockIdx.x, b = blockIdx.y, c = blockIdx.z;
    const int bp = b * NPATCH + p;
    const float* params = (c == 0) ? qp : (c == 1) ? kp : vp;
    const int lane = tid & 63, wv = tid >> 6;

    // ---- projection: 2 pixels/thread, DPP wave sums (no DS) ----
    float part[NQ];
    #pragma unroll
    for (int q = 0; q < NQ; ++q) part[q] = 0.0f;
    {
        int py = p / NPS, px = p % NPS;
        const float* xb = x + (size_t)b * 3 * 224 * 224;
        #pragma unroll
        for (int k = 0; k < 2; ++k) {
            int pix = tid + 128 * k;
            int off = (py * 16 + (pix >> 4)) * 224 + px * 16 + (pix & 15);
            float v = (xb[off] + xb[off + 50176] + xb[off + 100352]) * (1.0f / 3.0f);
            #pragma unroll
            for (int q = 0; q < NQ; ++q) part[q] += v * Wp[q * 256 + pix];
        }
    }
    if (tid < 40) {
        int l = tid / 20, g = tid - l * 20;
        float th = params[l * 32 + g];
        gC[tid] = 0.5f * cosf(2.0f * th);
        gS[tid] = 0.5f * sinf(2.0f * th);
    }
    #pragma unroll
    for (int q = 0; q < NQ; ++q) part[q] = wave_sum(part[q]);
    if (lane == 63) {
        #pragma unroll
        for (int q = 0; q < NQ; ++q) red2[wv][q] = part[q];
    }
    __syncthreads();
    if (tid < NQ) {
        float h = 0.5f * (red2[0][tid] + red2[1][tid] + bproj[tid]);
        chs[tid] = cosf(h); shs[tid] = sinf(h);
    }
    __syncthreads();

    // ---- init in L1: amp b0..b4 = q0..q4;
    //      tid m0=q10 m1=q5 m2=q6 m3=q7 m4=q11 m5=q8 | wave m6=q9 ----
    float amp[32];
    {
        float hi = ((tid &  1) ? shs[10] : chs[10]) *
                   ((tid &  2) ? shs[5]  : chs[5])  *
                   ((tid &  4) ? shs[6]  : chs[6])  *
                   ((tid &  8) ? shs[7]  : chs[7])  *
                   ((tid & 16) ? shs[11] : chs[11]) *
                   ((tid & 32) ? shs[8]  : chs[8])  *
                   ((tid & 64) ? shs[9]  : chs[9]);
        float pA[8], pB[4];
        #pragma unroll
        for (int i = 0; i < 8; ++i)
            pA[i] = ((i & 1) ? shs[0] : chs[0]) * ((i & 2) ? shs[1] : chs[1]) *
                    ((i & 4) ? shs[2] : chs[2]);
        #pragma unroll
        for (int i = 0; i < 4; ++i)
            pB[i] = ((i & 1) ? shs[3] : chs[3]) * ((i & 2) ? shs[4] : chs[4]);
        #pragma unroll
        for (int r = 0; r < 32; ++r) amp[r] = pA[r & 7] * pB[r >> 3] * hi;
    }

    // ---- 2 layers x 6 runs; 11 relayouts (7 barrier-free) ----
    #pragma unroll 1
    for (int l = 0; l < 2; ++l) {
        const int bb = l * 20;
        // R1 (L1: b=q0,q1,q2,q3,q4): p0(0,1) p1(2,3) p6(0,2) p7(1,3)
        apply_gate<1, 2>(amp, gC[bb+0], gS[bb+0]);
        apply_gate<4, 8>(amp, gC[bb+1], gS[bb+1]);
        apply_gate<1, 4>(amp, gC[bb+6], gS[bb+6]);
        apply_gate<2, 8>(amp, gC[bb+7], gS[bb+7]);
        relayout3<0>(amp, lds, tid);
        // R2 (L2: b=q4,q5,q6,q7,q8): p2(4,5) p3(6,7) p8(4,6) p9(5,7)
        apply_gate<1, 2>(amp, gC[bb+2], gS[bb+2]);
        apply_gate<4, 8>(amp, gC[bb+3], gS[bb+3]);
        apply_gate<1, 4>(amp, gC[bb+8], gS[bb+8]);
        apply_gate<2, 8>(amp, gC[bb+9], gS[bb+9]);
        relayout3<1>(amp, lds, tid);
        // R3 (L3: b=q9,q10,q11,q0,q8): p4(8,9) p5(10,11) p10(8,10) p11(9,11)
        apply_gate<16,1>(amp, gC[bb+4],  gS[bb+4]);
        apply_gate<2, 4>(amp, gC[bb+5],  gS[bb+5]);
        apply_gate<16,2>(amp, gC[bb+10], gS[bb+10]);
        apply_gate<1, 4>(amp, gC[bb+11], gS[bb+11]);
        relayout3<2>(amp, lds, tid);
        // R4 (L4: b=q0,q4,q5,q8,q1): p12(0,4) p13(1,5) p16(0,8)
        apply_gate<1, 2>(amp, gC[bb+12], gS[bb+12]);
        apply_gate<16,4>(amp, gC[bb+13], gS[bb+13]);
        apply_gate<1, 8>(amp, gC[bb+16], gS[bb+16]);
        relayout3<3>(amp, lds, tid);
        // R5 (L5: b=q1,q6,q9,q10,q2): p14(2,6) p17(1,9)
        apply_gate<16,2>(amp, gC[bb+14], gS[bb+14]);
        apply_gate<1, 4>(amp, gC[bb+17], gS[bb+17]);
        relayout3<4>(amp, lds, tid);
        // R6 (L6: b=q7,q10,q11,q2,q3): p15(3,7) p18(2,10) p19(3,11)
        apply_gate<16,1>(amp, gC[bb+15], gS[bb+15]);
        apply_gate<8, 2>(amp, gC[bb+18], gS[bb+18]);
        apply_gate<16,4>(amp, gC[bb+19], gS[bb+19]);
        if (l == 0) relayout3<5>(amp, lds, tid);
    }

    // ---- expvals in L6: amp b0=q7 b1=q10 b2=q11 b3=q2 b4=q3;
    //      tid m0=q5 m1=q0 m2=q1 m3=q6 m4=q8 m5=q4 | wave m6=q9 ----
    float T, Sq7, Sq10, Sq11, Sq2, Sq3;
    {
        float t1[16]; Sq7 = 0.0f;
        #pragma unroll
        for (int i = 0; i < 16; ++i) {
            float e = amp[2*i] * amp[2*i], o = amp[2*i+1] * amp[2*i+1];
            t1[i] = e + o; Sq7 += e - o;
        }
        float t2[8]; Sq10 = 0.0f;
        #pragma unroll
        for (int i = 0; i < 8; ++i) { t2[i] = t1[2*i] + t1[2*i+1]; Sq10 += t1[2*i] - t1[2*i+1]; }
        float t3[4]; Sq11 = 0.0f;
        #pragma unroll
        for (int i = 0; i < 4; ++i) { t3[i] = t2[2*i] + t2[2*i+1]; Sq11 += t2[2*i] - t2[2*i+1]; }
        float t4[2]; Sq2 = 0.0f;
        #pragma unroll
        for (int i = 0; i < 2; ++i) { t4[i] = t3[2*i] + t3[2*i+1]; Sq2 += t3[2*i] - t3[2*i+1]; }
        T = t4[0] + t4[1]; Sq3 = t4[0] - t4[1];
    }
    // lane-signed values, then DPP wave sums (no DS)
    float Vq5 = (tid &  1) ? -T : T;
    float Vq0 = (tid &  2) ? -T : T;
    float Vq1 = (tid &  4) ? -T : T;
    float Vq6 = (tid &  8) ? -T : T;
    float Vq8 = (tid & 16) ? -T : T;
    float Vq4 = (tid & 32) ? -T : T;
    T    = wave_sum(T);
    Vq5  = wave_sum(Vq5);  Vq0  = wave_sum(Vq0);  Vq1  = wave_sum(Vq1);
    Vq6  = wave_sum(Vq6);  Vq8  = wave_sum(Vq8);  Vq4  = wave_sum(Vq4);
    Sq7  = wave_sum(Sq7);  Sq10 = wave_sum(Sq10); Sq11 = wave_sum(Sq11);
    Sq2  = wave_sum(Sq2);  Sq3  = wave_sum(Sq3);
    if (lane == 63) {
        red2[wv][0]  = Vq0;  red2[wv][1]  = Vq1;  red2[wv][2]  = Sq2;
        red2[wv][3]  = Sq3;  red2[wv][4]  = Vq4;  red2[wv][5]  = Vq5;
        red2[wv][6]  = Vq6;  red2[wv][7]  = Sq7;  red2[wv][8]  = Vq8;
        red2[wv][9]  = T;    red2[wv][10] = Sq10; red2[wv][11] = Sq11;
    }
    __syncthreads();
    if (tid < NQ) {
        float v1 = red2[1][tid];
        float s = red2[0][tid] + ((tid == 9) ? -v1 : v1);   // wave bit = q9
        qkv[((size_t)c * (NB * NPATCH) + bp) * NQ + tid] = s;
    }
}

// ---- Kernel: attention ------------------------------------------------------
__global__ __launch_bounds__(256) void attn_kernel(
    const float* __restrict__ qkv,    // (3,784,12)
    float* __restrict__ outb)         // (4,2352)
{
    int tid = threadIdx.x;
    int qp = blockIdx.x, b = blockIdx.y;
    const float* Q = qkv;
    const float* K = qkv + NB * NPATCH * NQ;
    const float* V = qkv + 2 * NB * NPATCH * NQ;

    __shared__ float redm[4], reds[4], redv[4][NQ];

    float4 q0 = ((const float4*)(Q + (b * NPATCH + qp) * NQ))[0];
    float4 q1 = ((const float4*)(Q + (b * NPATCH + qp) * NQ))[1];
    float4 q2 = ((const float4*)(Q + (b * NPATCH + qp) * NQ))[2];

    float score = -1e30f;
    float4 v0, v1, v2;
    if (tid < NPATCH) {
        const float4* K4 = (const float4*)(K + (b * NPATCH + tid) * NQ);
        float4 k0 = K4[0], k1 = K4[1], k2 = K4[2];
        float s = q0.x*k0.x + q0.y*k0.y + q0.z*k0.z + q0.w*k0.w
                + q1.x*k1.x + q1.y*k1.y + q1.z*k1.z + q1.w*k1.w
                + q2.x*k2.x + q2.y*k2.y + q2.z*k2.z + q2.w*k2.w;
        score = s * SCALE_F;
        const float4* V4 = (const float4*)(V + (b * NPATCH + tid) * NQ);
        v0 = V4[0]; v1 = V4[1]; v2 = V4[2];
    }
    float m = score;
    #pragma unroll
    for (int o = 32; o > 0; o >>= 1) m = fmaxf(m, __shfl_down(m, o));
    int lane = tid & 63, wv = tid >> 6;
    if (lane == 0) redm[wv] = m;
    __syncthreads();
    float maxv = fmaxf(fmaxf(redm[0], redm[1]), fmaxf(redm[2], redm[3]));

    float w = (tid < NPATCH) ? expf(score - maxv) : 0.0f;
    float sm = w;
    #pragma unroll
    for (int o = 32; o > 0; o >>= 1) sm += __shfl_down(sm, o);
    if (lane == 0) reds[wv] = sm;

    float part[NQ];
    #pragma unroll
    for (int d = 0; d < NQ; d++) part[d] = 0.0f;
    if (tid < NPATCH) {
        part[0] = w*v0.x; part[1] = w*v0.y; part[2]  = w*v0.z; part[3]  = w*v0.w;
        part[4] = w*v1.x; part[5] = w*v1.y; part[6]  = w*v1.z; part[7]  = w*v1.w;
        part[8] = w*v2.x; part[9] = w*v2.y; part[10] = w*v2.z; part[11] = w*v2.w;
    }
    #pragma unroll
    for (int d = 0; d < NQ; d++) {
        #pragma unroll
        for (int o = 32; o > 0; o >>= 1) part[d] += __shfl_down(part[d], o);
    }
    if (lane == 0) {
        #pragma unroll
        for (int d = 0; d < NQ; d++) redv[wv][d] = part[d];
    }
    __syncthreads();
    if (tid < NQ) {
        float sumv = reds[0] + reds[1] + reds[2] + reds[3];
        float s = redv[0][tid] + redv[1][tid] + redv[2][tid] + redv[3][tid];
        outb[(size_t)b * FEATDIM + qp * NQ + tid] = s / sumv;
    }
}

// ---- Kernel: classifier -----------------------------------------------------
__global__ __launch_bounds__(256) void cls_kernel(
    const float* __restrict__ outb,   // (4,2352)
    const float* __restrict__ Wc,     // (1000,2352)
    const float* __restrict__ bc,     // (1000,)
    float* __restrict__ logits)       // (4,1000)
{
    int o = blockIdx.x, tid = threadIdx.x;
    float acc[NB] = {0.0f, 0.0f, 0.0f, 0.0f};
    const float4* w4 = (const float4*)(Wc + (size_t)o * FEATDIM);
    for (int j = tid; j < FEATDIM / 4; j += 256) {
        float4 w = w4[j];
        #pragma unroll
        for (int b = 0; b < NB; b++) {
            float4 ov = ((const float4*)(outb + (size_t)b * FEATDIM))[j];
            acc[b] += w.x*ov.x + w.y*ov.y + w.z*ov.z + w.w*ov.w;
        }
    }
    #pragma unroll
    for (int b = 0; b < NB; b++) {
        #pragma unroll
        for (int off = 32; off > 0; off >>= 1) acc[b] += __shfl_down(acc[b], off);
    }
    __shared__ float red[4][NB];
    int lane = tid & 63, wv = tid >> 6;
    if (lane == 0) {
        #pragma unroll
        for (int b = 0; b < NB; b++) red[wv][b] = acc[b];
    }
    __syncthreads();
    if (tid < NB) {
        float s = red[0][tid] + red[1][tid] + red[2][tid] + red[3][tid];
        logits[(size_t)tid * NCLS + o] = s + bc[o];
    }
}

// ---- Launch ----------------------------------------------------------------
extern "C" void kernel_launch(void* const* d_in, const int* in_sizes, int n_in,
                              void* d_out, int out_size, void* d_ws, size_t ws_size,
                              hipStream_t stream) {
    const float* x     = (const float*)d_in[0];
    const float* Wp    = (const float*)d_in[1];
    const float* bproj = (const float*)d_in[2];
    const float* qp    = (const float*)d_in[3];
    const float* kp    = (const float*)d_in[4];
    const float* vp    = (const float*)d_in[5];
    const float* Wc    = (const float*)d_in[6];
    const float* bc    = (const float*)d_in[7];
    float* logits = (float*)d_out;

    float* ws   = (float*)d_ws;
    float* qkv  = ws;                 // 3*784*12 = 28224 floats
    float* outb = ws + 28224;         // 4*2352   =  9408 floats

    qcirc_kernel<<<dim3(NPATCH, NB, 3), 128, 0, stream>>>(x, Wp, bproj, qp, kp, vp, qkv);
    attn_kernel <<<dim3(NPATCH, NB),    256, 0, stream>>>(qkv, outb);
    cls_kernel  <<<NCLS,                256, 0, stream>>>(outb, Wc, bc, logits);
}